// Round 1
// baseline (1989.433 us; speedup 1.0000x reference)
//
#include <hip/hip_runtime.h>
#include <hip/hip_fp16.h>

// Problem constants
#define BB 16
#define TT 256
#define HH 512
#define EE 256
#define VV 32000

using half8   = __attribute__((ext_vector_type(8))) _Float16;
using float4v = __attribute__((ext_vector_type(4))) float;
typedef unsigned long long u64;

// ---------------- ws layout (bytes) ----------------
#define WS_WFC16   0u                       // 32000*512*2 = 32768000
#define WS_XG      32768000u                // 4096*256*2  = 2097152
#define WS_WIH0    34865152u                // 512*256*2   = 262144
#define WS_WIH1    35127296u                // 512*512*2   = 524288
#define WS_XP0     35651584u                // 256*16*512*4= 8388608  (t-major [T][B][H], incl b_ih0+b_hh0)
#define WS_XP1     44040192u                // 8388608               (t-major [T][B][H], incl b_ih1+b_hh1)
#define WS_H0EX    52428800u                // 256*16*512*2= 4194304 (per-t packed f16 pairs)
#define WS_OUT2F16 56623104u                // 4096*512*2  = 4194304
#define WS_FLAGS   60817408u                // 16384 (flags0: 256*8 u32, flag1x: 256 u32)
#define WS_NEEDED  60833792u

// ---------------- tiny prep kernels ----------------
__global__ void init_flags_k(unsigned* f) {
    f[blockIdx.x * 256 + threadIdx.x] = 0u;   // 9*256 = 2304 entries
}

__global__ void cvt_f32_f16_k(const float* __restrict__ s, _Float16* __restrict__ d, int n) {
    int i = blockIdx.x * 256 + threadIdx.x;
    if (i < n) d[i] = (_Float16)s[i];
}

__global__ void gather_embed_k(const int* __restrict__ X, const float* __restrict__ emb,
                               _Float16* __restrict__ xg) {
    int m = blockIdx.x;            // m = b*T + t
    int e = threadIdx.x;           // 256 threads
    int row = X[m];
    xg[m * EE + e] = (_Float16)emb[(size_t)row * EE + e];
}

// ---------------- generic f16 GEMM: C[M,N] = A[M,K] * B[N,K]^T + bias0 + bias1 ----------------
// 128x128 tile, BK=32, 256 threads (4 waves, each 64x64)
template <bool PERM>  // PERM: store C at [t][b][n] with row=b*256+t (for xp0)
__global__ __launch_bounds__(256)
void gemm_f16_k(const _Float16* __restrict__ A, const _Float16* __restrict__ Bm,
                const float* __restrict__ bias0, const float* __restrict__ bias1,
                float* __restrict__ C, int M, int N, int K) {
    __shared__ _Float16 As[128][40];
    __shared__ _Float16 Bs[128][40];
    const int tid = threadIdx.x;
    const int l = tid & 63, w = tid >> 6;
    const int ntiles = N >> 7;
    const int m0 = (blockIdx.x / ntiles) << 7;
    const int n0 = (blockIdx.x % ntiles) << 7;
    const int wr = (w >> 1) << 6, wc = (w & 1) << 6;
    const int lrow = tid >> 1, lseg = (tid & 1) << 4;
    const int ar = l & 15, ak = (l >> 4) << 3;

    float4v acc[4][4] = {};

    for (int kt = 0; kt < K; kt += 32) {
        const _Float16* ga = A  + (size_t)(m0 + lrow) * K + kt + lseg;
        const _Float16* gb = Bm + (size_t)(n0 + lrow) * K + kt + lseg;
        *(int4*)&As[lrow][lseg]     = *(const int4*)ga;
        *(int4*)&As[lrow][lseg + 8] = *(const int4*)(ga + 8);
        *(int4*)&Bs[lrow][lseg]     = *(const int4*)gb;
        *(int4*)&Bs[lrow][lseg + 8] = *(const int4*)(gb + 8);
        __syncthreads();

        half8 af[4], bf[4];
#pragma unroll
        for (int m = 0; m < 4; ++m) af[m] = *(half8*)&As[wr + m * 16 + ar][ak];
#pragma unroll
        for (int n = 0; n < 4; ++n) bf[n] = *(half8*)&Bs[wc + n * 16 + ar][ak];
#pragma unroll
        for (int m = 0; m < 4; ++m)
#pragma unroll
            for (int n = 0; n < 4; ++n)
                acc[m][n] = __builtin_amdgcn_mfma_f32_16x16x32_f16(af[m], bf[n], acc[m][n], 0, 0, 0);
        __syncthreads();
    }

#pragma unroll
    for (int m = 0; m < 4; ++m) {
#pragma unroll
        for (int n = 0; n < 4; ++n) {
            const int col = n0 + wc + n * 16 + (l & 15);
            float bv = (bias0 ? bias0[col] : 0.f) + (bias1 ? bias1[col] : 0.f);
#pragma unroll
            for (int r = 0; r < 4; ++r) {
                const int row = m0 + wr + m * 16 + ((l >> 4) << 2) + r;
                float v = acc[m][n][r] + bv;
                if (PERM) {
                    int t = row & 255, b = row >> 8;
                    C[(size_t)((t << 4) + b) * HH + col] = v;
                } else {
                    C[(size_t)row * N + col] = v;
                }
            }
        }
    }
}

// fast tanh: 1 - 2/(e^{2x}+1).  v_exp + v_rcp based, ~1e-6 abs err (<< f16 quantization)
__device__ __forceinline__ float tanh_fast(float x) {
    float e = __expf(2.0f * x);
    return 1.0f - 2.0f * __builtin_amdgcn_rcpf(e + 1.0f);
}

// ---------------- fused RNN pipeline ----------------
// grid = 34 blocks x 512 threads.
//   block 0: layer-0 recurrence  (whole layer on ONE CU: W_hh0 in 192 VGPR/wave + 128KB LDS)
//   block 1: layer-1 recurrence  (same structure, consumes xp1)
//   blocks 2..33: xp1 stage: per t, xp1[t] = h0[t] @ W_ih1^T + b_ih1 + b_hh1  (t-striped, feed-forward)
// Recurrence critical path is LDS+MFMA only; all global publishes are fire-and-forget
// (raw s_barrier, no vmcnt drain on the chain). Flags deferred one step so release vmcnt(0) is free.
__global__ __launch_bounds__(512, 2)
void rnn_pipe_k(const float* __restrict__ Whh0, const float* __restrict__ Whh1,
                const _Float16* __restrict__ Wih1f16,
                const float* __restrict__ bih1, const float* __restrict__ bhh1,
                const float* __restrict__ xp0, float* __restrict__ xp1,
                unsigned* __restrict__ h0ex,
                _Float16* __restrict__ out2f16, float* __restrict__ out_hidden,
                float* __restrict__ out2f32,
                unsigned* __restrict__ flags0, unsigned* __restrict__ flag1x)
{
    __shared__ _Float16 hbuf[16][520];            // h[t-1], 16.6 KB (stride 520: 2-way banks max)
    __shared__ _Float16 wlds[8 * 4 * 4 * 64 * 8]; // K-tiles 12..15 as frags, 128 KB, conflict-free

    const int tid = threadIdx.x;
    const int l = tid & 63, w = tid >> 6;
    const int lq = l >> 4;          // 0..3
    const int kq = lq << 3;         // {0,8,16,24}
    const int c15 = l & 15;
    const int bi = blockIdx.x;

    if (bi < 2) {
        // ================= recurrence block (one per layer) =================
        const int layer = bi;
        const float* Whh = layer ? Whh1 : Whh0;

        // --- persistent W_hh fragments: 12 K-tiles in VGPRs, 4 in LDS ---
        half8 wf[4][12];
#pragma unroll
        for (int ct = 0; ct < 4; ++ct) {
            const int col = w * 64 + ct * 16 + c15;
            const float* wrow = Whh + (size_t)col * HH;
#pragma unroll
            for (int kt = 0; kt < 16; ++kt) {
                const float* s = wrow + kt * 32 + kq;
                float4v f0 = *(const float4v*)s;
                float4v f1 = *(const float4v*)(s + 4);
                half8 h;
#pragma unroll
                for (int i = 0; i < 4; ++i) { h[i] = (_Float16)f0[i]; h[i + 4] = (_Float16)f1[i]; }
                if (kt < 12) wf[ct][kt] = h;
                else *(half8*)&wlds[((((w * 4 + ct) * 4) + (kt - 12)) * 64 + l) * 8] = h;
            }
        }

        // --- acc holds xp[t]; MFMA accumulates the recurrence on top ---
        float4v acc[4], accn[4];
        if (layer == 0) {
#pragma unroll
            for (int ct = 0; ct < 4; ++ct) {
                const int col = w * 64 + ct * 16 + c15;
#pragma unroll
                for (int r = 0; r < 4; ++r)
                    acc[ct][r] = xp0[(size_t)(lq * 4 + r) * HH + col];
            }
        } else {
            while (!__hip_atomic_load(&flag1x[0], __ATOMIC_ACQUIRE, __HIP_MEMORY_SCOPE_AGENT))
                __builtin_amdgcn_s_sleep(2);
#pragma unroll
            for (int ct = 0; ct < 4; ++ct) {
                const int col = w * 64 + ct * 16 + c15;
#pragma unroll
                for (int r = 0; r < 4; ++r)
                    acc[ct][r] = __hip_atomic_load(&xp1[(size_t)(lq * 4 + r) * HH + col],
                                                   __ATOMIC_RELAXED, __HIP_MEMORY_SCOPE_AGENT);
            }
        }
        __syncthreads();   // wlds visible

        for (int t = 0; t < TT; ++t) {
            // ---- B: recurrence MFMAs (h[t-1] from LDS; 4 independent acc chains) ----
            if (t > 0) {
#pragma unroll
                for (int kt = 0; kt < 16; ++kt) {
                    half8 a = *(const half8*)&hbuf[c15][kt * 32 + kq];
                    half8 b0, b1, b2, b3;
                    if (kt < 12) {
                        b0 = wf[0][kt]; b1 = wf[1][kt]; b2 = wf[2][kt]; b3 = wf[3][kt];
                    } else {
                        b0 = *(const half8*)&wlds[((((w * 4 + 0) * 4) + (kt - 12)) * 64 + l) * 8];
                        b1 = *(const half8*)&wlds[((((w * 4 + 1) * 4) + (kt - 12)) * 64 + l) * 8];
                        b2 = *(const half8*)&wlds[((((w * 4 + 2) * 4) + (kt - 12)) * 64 + l) * 8];
                        b3 = *(const half8*)&wlds[((((w * 4 + 3) * 4) + (kt - 12)) * 64 + l) * 8];
                    }
                    acc[0] = __builtin_amdgcn_mfma_f32_16x16x32_f16(a, b0, acc[0], 0, 0, 0);
                    acc[1] = __builtin_amdgcn_mfma_f32_16x16x32_f16(a, b1, acc[1], 0, 0, 0);
                    acc[2] = __builtin_amdgcn_mfma_f32_16x16x32_f16(a, b2, acc[2], 0, 0, 0);
                    acc[3] = __builtin_amdgcn_mfma_f32_16x16x32_f16(a, b3, acc[3], 0, 0, 0);
                }
            }

            // ---- A: deferred flag for t-1 (layer0) — prior step's publishes are drained by now ----
            if (layer == 0 && t > 0) {
                asm volatile("s_waitcnt vmcnt(0)" ::: "memory");
                if (l == 0)
                    __hip_atomic_store(&flags0[(t - 1) * 8 + w], 1u,
                                       __ATOMIC_RELAXED, __HIP_MEMORY_SCOPE_AGENT);
            }

            // ---- C: prefetch xp[t+1] into accn (fire-and-forget; consumed next step) ----
            if (t + 1 < TT) {
                if (layer == 0) {
#pragma unroll
                    for (int ct = 0; ct < 4; ++ct) {
                        const int col = w * 64 + ct * 16 + c15;
#pragma unroll
                        for (int r = 0; r < 4; ++r)
                            accn[ct][r] = xp0[(size_t)((t + 1) * 16 + lq * 4 + r) * HH + col];
                    }
                } else {
                    while (!__hip_atomic_load(&flag1x[t + 1], __ATOMIC_ACQUIRE, __HIP_MEMORY_SCOPE_AGENT))
                        __builtin_amdgcn_s_sleep(2);
#pragma unroll
                    for (int ct = 0; ct < 4; ++ct) {
                        const int col = w * 64 + ct * 16 + c15;
#pragma unroll
                        for (int r = 0; r < 4; ++r)
                            accn[ct][r] = __hip_atomic_load(&xp1[(size_t)((t + 1) * 16 + lq * 4 + r) * HH + col],
                                                            __ATOMIC_RELAXED, __HIP_MEMORY_SCOPE_AGENT);
                    }
                }
            }

            // ---- D: tanh + f32 outputs + pack f16 pairs ----
            unsigned pk[4][4];
#pragma unroll
            for (int ct = 0; ct < 4; ++ct) {
                const int col = w * 64 + ct * 16 + c15;
#pragma unroll
                for (int r = 0; r < 4; ++r) {
                    const int b = lq * 4 + r;
                    float hv = tanh_fast(acc[ct][r]);
                    if (layer)
                        out2f32[((size_t)(b << 8) + t) * HH + col] = hv;
                    if (t == TT - 1)
                        out_hidden[(size_t)(layer * BB + b) * HH + col] = hv;
                    unsigned short mu = __builtin_bit_cast(unsigned short, (_Float16)hv);
                    int ov = __shfl_xor((int)mu, 1, 64);
                    pk[ct][r] = (unsigned)mu | ((unsigned)ov << 16);   // valid on even lanes
                }
            }

            // ---- E: global publish (fire-and-forget) ----
            if (layer == 0) {
                unsigned* dst = h0ex + (size_t)t * 4096;
#pragma unroll
                for (int ct = 0; ct < 4; ++ct) {
                    const int col = w * 64 + ct * 16 + c15;
#pragma unroll
                    for (int r = 0; r < 4; ++r)
                        if ((l & 1) == 0)
                            __hip_atomic_store(&dst[(lq * 4 + r) * 256 + (col >> 1)], pk[ct][r],
                                               __ATOMIC_RELAXED, __HIP_MEMORY_SCOPE_AGENT);
                }
            } else {
#pragma unroll
                for (int ct = 0; ct < 4; ++ct) {
                    const int col = w * 64 + ct * 16 + c15;
#pragma unroll
                    for (int r = 0; r < 4; ++r)
                        if ((l & 1) == 0)
                            *(unsigned*)&out2f16[((size_t)((lq * 4 + r) << 8) + t) * HH + col] = pk[ct][r];
                }
            }

            // ---- F: raw barrier — all waves done reading hbuf (no vmcnt drain!) ----
            asm volatile("" ::: "memory");
            __builtin_amdgcn_s_barrier();
            asm volatile("" ::: "memory");

            // ---- G: write h[t] into hbuf; LDS-only fence + raw barrier ----
#pragma unroll
            for (int ct = 0; ct < 4; ++ct) {
                const int col = w * 64 + ct * 16 + c15;
#pragma unroll
                for (int r = 0; r < 4; ++r)
                    if ((l & 1) == 0)
                        *(unsigned*)&hbuf[lq * 4 + r][col] = pk[ct][r];
            }
            asm volatile("s_waitcnt lgkmcnt(0)" ::: "memory");
            __builtin_amdgcn_s_barrier();
            asm volatile("" ::: "memory");

            // ---- H: roll prefetched xp into acc ----
            if (t + 1 < TT) {
#pragma unroll
                for (int ct = 0; ct < 4; ++ct) acc[ct] = accn[ct];
            }
        }

        if (layer == 0) {
            asm volatile("s_waitcnt vmcnt(0)" ::: "memory");
            if (l == 0)
                __hip_atomic_store(&flags0[(TT - 1) * 8 + w], 1u,
                                   __ATOMIC_RELAXED, __HIP_MEMORY_SCOPE_AGENT);
        }
    } else {
        // ================= xp1 stage: t-striped feed-forward GEMM =================
        const int stripe = bi - 2;               // 0..31, handles t = stripe + 32j
        float bsum[4];
#pragma unroll
        for (int ct = 0; ct < 4; ++ct) {
            const int col = w * 64 + ct * 16 + c15;
            bsum[ct] = bih1[col] + bhh1[col];
        }
        const int base64 = c15 * 128 + lq * 2;

        for (int j = 0; j < 8; ++j) {
            const int t = stripe + 32 * j;
            // poll all 8 layer-0 wave flags for step t
            for (;;) {
                unsigned v = 1u;
                if (l < 8)
                    v = __hip_atomic_load(&flags0[t * 8 + l], __ATOMIC_ACQUIRE, __HIP_MEMORY_SCOPE_AGENT);
                if (__all(v != 0)) break;
                __builtin_amdgcn_s_sleep(2);
            }
            // h0[t] A-fragments straight to registers (agent-scope, bypasses stale L2)
            half8 af[16];
            const u64* pA = (const u64*)h0ex + (size_t)t * 2048;
#pragma unroll
            for (int kt = 0; kt < 16; ++kt) {
                u64 d0 = __hip_atomic_load(pA + base64 + kt * 8,     __ATOMIC_RELAXED, __HIP_MEMORY_SCOPE_AGENT);
                u64 d1 = __hip_atomic_load(pA + base64 + kt * 8 + 1, __ATOMIC_RELAXED, __HIP_MEMORY_SCOPE_AGENT);
                union { u64 u[2]; half8 h; } cv;
                cv.u[0] = d0; cv.u[1] = d1;
                af[kt] = cv.h;
            }
            float4v acc[4];
#pragma unroll
            for (int ct = 0; ct < 4; ++ct) {
                acc[ct][0] = bsum[ct]; acc[ct][1] = bsum[ct];
                acc[ct][2] = bsum[ct]; acc[ct][3] = bsum[ct];
            }
#pragma unroll
            for (int ct = 0; ct < 4; ++ct) {
                const int col = w * 64 + ct * 16 + c15;
                const _Float16* wp = Wih1f16 + (size_t)col * HH + kq;
#pragma unroll
                for (int kt = 0; kt < 16; ++kt) {
                    half8 bf = *(const half8*)(wp + kt * 32);
                    acc[ct] = __builtin_amdgcn_mfma_f32_16x16x32_f16(af[kt], bf, acc[ct], 0, 0, 0);
                }
            }
            // publish xp1[t] (agent scope) then one flag for the whole t
#pragma unroll
            for (int ct = 0; ct < 4; ++ct) {
                const int col = w * 64 + ct * 16 + c15;
#pragma unroll
                for (int r = 0; r < 4; ++r)
                    __hip_atomic_store(&xp1[(size_t)(t * 16 + lq * 4 + r) * HH + col], acc[ct][r],
                                       __ATOMIC_RELAXED, __HIP_MEMORY_SCOPE_AGENT);
            }
            __syncthreads();   // implicit vmcnt(0) per wave before barrier -> all stores drained
            if (tid == 0)
                __hip_atomic_store(&flag1x[t], 1u, __ATOMIC_RELEASE, __HIP_MEMORY_SCOPE_AGENT);
        }
    }
}

// ---------------- launch ----------------
extern "C" void kernel_launch(void* const* d_in, const int* in_sizes, int n_in,
                              void* d_out, int out_size, void* d_ws, size_t ws_size,
                              hipStream_t stream) {
    if (ws_size < WS_NEEDED) return;  // loud failure rather than corruption

    const int*   X     = (const int*)d_in[0];
    const float* emb   = (const float*)d_in[1];
    const float* Wih0  = (const float*)d_in[2];
    const float* Whh0  = (const float*)d_in[3];
    const float* bih0  = (const float*)d_in[4];
    const float* bhh0  = (const float*)d_in[5];
    const float* Wih1  = (const float*)d_in[6];
    const float* Whh1  = (const float*)d_in[7];
    const float* bih1  = (const float*)d_in[8];
    const float* bhh1  = (const float*)d_in[9];
    const float* Wfc   = (const float*)d_in[10];
    const float* bfc   = (const float*)d_in[11];

    char* ws = (char*)d_ws;
    _Float16* Wfc16   = (_Float16*)(ws + WS_WFC16);
    _Float16* xg      = (_Float16*)(ws + WS_XG);
    _Float16* Wih0f16 = (_Float16*)(ws + WS_WIH0);
    _Float16* Wih1f16 = (_Float16*)(ws + WS_WIH1);
    float*    xp0     = (float*)(ws + WS_XP0);
    float*    xp1     = (float*)(ws + WS_XP1);
    unsigned* h0ex    = (unsigned*)(ws + WS_H0EX);
    _Float16* o2f16   = (_Float16*)(ws + WS_OUT2F16);
    unsigned* flags0  = (unsigned*)(ws + WS_FLAGS);
    unsigned* flag1x  = flags0 + TT * 8;

    float* logits     = (float*)d_out;                          // [16,256,32000]
    float* hidden     = (float*)d_out + (size_t)BB * TT * VV;   // [2,16,512]
    float* out2       = hidden + 2 * BB * HH;                   // [16,256,512]

    // prep
    hipLaunchKernelGGL(init_flags_k, dim3(9), dim3(256), 0, stream, flags0);
    hipLaunchKernelGGL(gather_embed_k, dim3(BB * TT), dim3(256), 0, stream, X, emb, xg);
    hipLaunchKernelGGL(cvt_f32_f16_k, dim3((HH * EE) / 256), dim3(256), 0, stream, Wih0, Wih0f16, HH * EE);
    hipLaunchKernelGGL(cvt_f32_f16_k, dim3((HH * HH) / 256), dim3(256), 0, stream, Wih1, Wih1f16, HH * HH);
    hipLaunchKernelGGL(cvt_f32_f16_k, dim3((VV * HH) / 256), dim3(256), 0, stream, Wfc, Wfc16, VV * HH);

    // layer-0 input projection -> xp0 (t-major), bias = b_ih0 + b_hh0
    hipLaunchKernelGGL((gemm_f16_k<true>), dim3((4096 / 128) * (HH / 128)), dim3(256), 0, stream,
                       xg, Wih0f16, bih0, bhh0, xp0, 4096, HH, EE);

    // fused pipelined 2-layer recurrence (2 rec blocks + 32 xp1-stage blocks)
    hipLaunchKernelGGL(rnn_pipe_k, dim3(34), dim3(512), 0, stream,
                       Whh0, Whh1, Wih1f16, bih1, bhh1, xp0, xp1,
                       h0ex, o2f16, hidden, out2, flags0, flag1x);

    // final FC: logits = out2 @ Wfc^T + b_fc
    hipLaunchKernelGGL((gemm_f16_k<false>), dim3((4096 / 128) * (VV / 128)), dim3(256), 0, stream,
                       o2f16, Wfc16, bfc, nullptr, logits, 4096, VV, HH);
}